// Round 5
// baseline (1527.083 us; speedup 1.0000x reference)
//
#include <hip/hip_runtime.h>
#include <hip/hip_bf16.h>

#define H 128
#define NEG 0.01f
#define NBLK 512

typedef __bf16 bf16;
typedef bf16 bf16x4 __attribute__((ext_vector_type(4)));
typedef bf16 bf16x8 __attribute__((ext_vector_type(8)));
typedef float f32x4 __attribute__((ext_vector_type(4)));
typedef float f32x2 __attribute__((ext_vector_type(2)));
typedef unsigned int u32;

// ---- fp8 e4m3 (OCP) pack/unpack: 8 elems <-> 8 bytes ----
__device__ __forceinline__ void dec8(uint2 p, float f[8]) {
    f32x2 a = __builtin_amdgcn_cvt_pk_f32_fp8(p.x, false);
    f32x2 b = __builtin_amdgcn_cvt_pk_f32_fp8(p.x, true);
    f32x2 c = __builtin_amdgcn_cvt_pk_f32_fp8(p.y, false);
    f32x2 d = __builtin_amdgcn_cvt_pk_f32_fp8(p.y, true);
    f[0] = a[0]; f[1] = a[1]; f[2] = b[0]; f[3] = b[1];
    f[4] = c[0]; f[5] = c[1]; f[6] = d[0]; f[7] = d[1];
}
__device__ __forceinline__ uint2 enc8(const float f[8]) {
    int lo = 0, hi = 0;
    lo = __builtin_amdgcn_cvt_pk_fp8_f32(f[0], f[1], lo, false);
    lo = __builtin_amdgcn_cvt_pk_fp8_f32(f[2], f[3], lo, true);
    hi = __builtin_amdgcn_cvt_pk_fp8_f32(f[4], f[5], hi, false);
    hi = __builtin_amdgcn_cvt_pk_fp8_f32(f[6], f[7], hi, true);
    uint2 r; r.x = (u32)lo; r.y = (u32)hi; return r;
}

// ---- grid barrier: one-shot counters (zeroed host-side), agent-scope rel/acq ----
__device__ __forceinline__ void gbar(int* bar, int idx) {
    __syncthreads();
    if (threadIdx.x == 0) {
        __threadfence();
        __hip_atomic_fetch_add(bar + idx, 1, __ATOMIC_RELEASE, __HIP_MEMORY_SCOPE_AGENT);
        while (__hip_atomic_load(bar + idx, __ATOMIC_ACQUIRE, __HIP_MEMORY_SCOPE_AGENT) < NBLK)
            __builtin_amdgcn_s_sleep(8);
        __threadfence();
    }
    __syncthreads();
}

// ---- gemm0 phase: h0_fp8[M,128] = A_f32[M,256] @ Wn + bn, fused colsum ----
__device__ __forceinline__ void gemm0_phase(const float* __restrict__ A, const float* __restrict__ Bw,
        const float* __restrict__ bias, uint2* __restrict__ Cg, float* __restrict__ colsum,
        int M, bf16 (*As)[136], bf16 (*Bs)[136], float* cs)
{
    const int tid = threadIdx.x;
    const int wave = tid >> 6, lane = tid & 63;
    const int sub = lane & 15, rg = lane >> 4;
    if (tid < 128) cs[tid] = 0.f;
    for (int tile = blockIdx.x; tile * 64 < M; tile += NBLK) {
        const int blockRow = tile * 64;
        f32x4 acc[8];
#pragma unroll
        for (int t = 0; t < 8; t++) acc[t] = (f32x4){0.f, 0.f, 0.f, 0.f};
        for (int k0 = 0; k0 < 256; k0 += 128) {
#pragma unroll
            for (int it = 0; it < 8; it++) {
                int s = it * 256 + tid;
                int row = s >> 5, f4 = (s & 31) * 4;
                int grow = blockRow + row; if (grow > M - 1) grow = M - 1;
                const float4 v = *(const float4*)(A + (size_t)grow * 256 + k0 + f4);
                bf16x4 w = { (bf16)v.x, (bf16)v.y, (bf16)v.z, (bf16)v.w };
                *(bf16x4*)&As[row][f4] = w;
            }
#pragma unroll
            for (int it = 0; it < 16; it++) {
                int s = it * 256 + tid;
                int kr = s >> 5, f4 = (s & 31) * 4;
                const float4 v = *(const float4*)(Bw + (size_t)(k0 + kr) * H + f4);
                Bs[f4 + 0][kr] = (bf16)v.x;
                Bs[f4 + 1][kr] = (bf16)v.y;
                Bs[f4 + 2][kr] = (bf16)v.z;
                Bs[f4 + 3][kr] = (bf16)v.w;
            }
            __syncthreads();
#pragma unroll
            for (int kk = 0; kk < 128; kk += 32) {
                bf16x8 af = *(const bf16x8*)&As[wave * 16 + sub][kk + rg * 8];
#pragma unroll
                for (int t = 0; t < 8; t++) {
                    bf16x8 bfv = *(const bf16x8*)&Bs[t * 16 + sub][kk + rg * 8];
                    acc[t] = __builtin_amdgcn_mfma_f32_16x16x32_bf16(af, bfv, acc[t], 0, 0, 0);
                }
            }
            __syncthreads();
        }
        bf16* stg = (bf16*)&Bs[0][0];   // [64][136]
        const int rbase0 = wave * 16 + rg * 4;
        float lsum[8];
#pragma unroll
        for (int t = 0; t < 8; t++) lsum[t] = 0.f;
#pragma unroll
        for (int r = 0; r < 4; r++) {
            int rowt = rbase0 + r;
            if (blockRow + rowt < M) {
#pragma unroll
                for (int t = 0; t < 8; t++) {
                    int col = t * 16 + sub;
                    float val = acc[t][r] + bias[col];
                    lsum[t] += val;
                    stg[rowt * 136 + col] = (bf16)val;
                }
            }
        }
#pragma unroll
        for (int t = 0; t < 8; t++) {
            lsum[t] += __shfl_xor(lsum[t], 16);
            lsum[t] += __shfl_xor(lsum[t], 32);
        }
        if (rg == 0) {
#pragma unroll
            for (int t = 0; t < 8; t++) atomicAdd(&cs[t * 16 + sub], lsum[t]);
        }
        __syncthreads();
#pragma unroll
        for (int it = 0; it < 4; it++) {
            int s = it * 256 + tid;
            int row = s >> 4, cg = s & 15;
            int grow = blockRow + row;
            if (grow < M) {
                float f[8];
#pragma unroll
                for (int k = 0; k < 8; k++) f[k] = (float)stg[row * 136 + cg * 8 + k];
                Cg[(size_t)grow * 16 + cg] = enc8(f);
            }
        }
        __syncthreads();
    }
    if (tid < 128) atomicAdd(&colsum[tid], cs[tid]);
}

// ---- layer gemm phase: leakyrelu(A_bf16[M,128] @ Wgcn + b); optional hs_fp8 = val/deg ----
template<bool WRITE_NEXT>
__device__ __forceinline__ void gemmL_phase(const bf16* __restrict__ A, const float* __restrict__ Bw,
        const float* __restrict__ bias, const float* __restrict__ deg, uint2* __restrict__ hs,
        float* __restrict__ colsum, int M, bf16 (*As)[136], bf16 (*Bs)[136], float* cs)
{
    const int tid = threadIdx.x;
    const int wave = tid >> 6, lane = tid & 63;
    const int sub = lane & 15, rg = lane >> 4;
    if (tid < 128) cs[tid] = 0.f;
    for (int tile = blockIdx.x; tile * 64 < M; tile += NBLK) {
        const int blockRow = tile * 64;
#pragma unroll
        for (int it = 0; it < 4; it++) {
            int s = it * 256 + tid;
            int row = s >> 4, ch = (s & 15) * 8;
            int grow = blockRow + row; if (grow > M - 1) grow = M - 1;
            bf16x8 v = *(const bf16x8*)(A + (size_t)grow * H + ch);
            *(bf16x8*)&As[row][ch] = v;
        }
#pragma unroll
        for (int it = 0; it < 16; it++) {
            int s = it * 256 + tid;
            int kr = s >> 5, f4 = (s & 31) * 4;
            const float4 v = *(const float4*)(Bw + (size_t)kr * H + f4);
            Bs[f4 + 0][kr] = (bf16)v.x;
            Bs[f4 + 1][kr] = (bf16)v.y;
            Bs[f4 + 2][kr] = (bf16)v.z;
            Bs[f4 + 3][kr] = (bf16)v.w;
        }
        __syncthreads();
        f32x4 acc[8];
#pragma unroll
        for (int t = 0; t < 8; t++) acc[t] = (f32x4){0.f, 0.f, 0.f, 0.f};
#pragma unroll
        for (int kk = 0; kk < 128; kk += 32) {
            bf16x8 af = *(const bf16x8*)&As[wave * 16 + sub][kk + rg * 8];
#pragma unroll
            for (int t = 0; t < 8; t++) {
                bf16x8 bfv = *(const bf16x8*)&Bs[t * 16 + sub][kk + rg * 8];
                acc[t] = __builtin_amdgcn_mfma_f32_16x16x32_bf16(af, bfv, acc[t], 0, 0, 0);
            }
        }
        __syncthreads();
        bf16* stg = (bf16*)&Bs[0][0];
        const int rbase0 = wave * 16 + rg * 4;
        float lsum[8];
#pragma unroll
        for (int t = 0; t < 8; t++) lsum[t] = 0.f;
#pragma unroll
        for (int r = 0; r < 4; r++) {
            int rowt = rbase0 + r;
            int grow = blockRow + rowt;
            if (grow < M) {
                float rd = WRITE_NEXT ? (1.0f / deg[grow]) : 0.f;
#pragma unroll
                for (int t = 0; t < 8; t++) {
                    int col = t * 16 + sub;
                    float val = acc[t][r] + bias[col];
                    val = (val > 0.f) ? val : NEG * val;
                    lsum[t] += val;
                    if (WRITE_NEXT) stg[rowt * 136 + col] = (bf16)(val * rd);
                }
            }
        }
#pragma unroll
        for (int t = 0; t < 8; t++) {
            lsum[t] += __shfl_xor(lsum[t], 16);
            lsum[t] += __shfl_xor(lsum[t], 32);
        }
        if (rg == 0) {
#pragma unroll
            for (int t = 0; t < 8; t++) atomicAdd(&cs[t * 16 + sub], lsum[t]);
        }
        __syncthreads();
        if (WRITE_NEXT) {
#pragma unroll
            for (int it = 0; it < 4; it++) {
                int s = it * 256 + tid;
                int row = s >> 4, cg = s & 15;
                int grow = blockRow + row;
                if (grow < M) {
                    float f[8];
#pragma unroll
                    for (int k = 0; k < 8; k++) f[k] = (float)stg[row * 136 + cg * 8 + k];
                    hs[(size_t)grow * 16 + cg] = enc8(f);
                }
            }
        }
        __syncthreads();
    }
    if (tid < 128) atomicAdd(&colsum[tid], cs[tid]);
}

// ---- agg phases (grid-stride, 1 wave/node, 16-lane groups x 4 edges in flight) ----
__device__ __forceinline__ void agg0_phase(const uint2* __restrict__ hg, const int* __restrict__ row_ptr,
        const int* __restrict__ ssrc, const float* __restrict__ deg, uint2* __restrict__ hs, int n)
{
    const int wave = threadIdx.x >> 6, lane = threadIdx.x & 63;
    const int g = lane >> 4, sub = lane & 15;
    for (int b0 = blockIdx.x * 4; b0 < n; b0 += NBLK * 4) {
        int v = b0 + wave;
        if (v < n) {
            int e0 = row_ptr[v], e1 = row_ptr[v + 1];
            float d = deg[v];
            float acc[8];
#pragma unroll
            for (int k = 0; k < 8; k++) acc[k] = 0.f;
            for (int base = e0; base < e1; base += 16) {
                int mye = base + g * 4;
                int idx[4]; float w[4];
#pragma unroll
                for (int j = 0; j < 4; j++) {
                    int e = mye + j;
                    w[j] = (e < e1) ? 1.0f : 0.0f;
                    idx[j] = ssrc[e < e1 ? e : e1 - 1];
                }
                uint2 x0 = hg[(size_t)idx[0] * 16 + sub];
                uint2 x1 = hg[(size_t)idx[1] * 16 + sub];
                uint2 x2 = hg[(size_t)idx[2] * 16 + sub];
                uint2 x3 = hg[(size_t)idx[3] * 16 + sub];
                float f0[8], f1[8], f2[8], f3[8];
                dec8(x0, f0); dec8(x1, f1); dec8(x2, f2); dec8(x3, f3);
#pragma unroll
                for (int k = 0; k < 8; k++) acc[k] = fmaf(w[0], f0[k], acc[k]);
#pragma unroll
                for (int k = 0; k < 8; k++) acc[k] = fmaf(w[1], f1[k], acc[k]);
#pragma unroll
                for (int k = 0; k < 8; k++) acc[k] = fmaf(w[2], f2[k], acc[k]);
#pragma unroll
                for (int k = 0; k < 8; k++) acc[k] = fmaf(w[3], f3[k], acc[k]);
            }
#pragma unroll
            for (int k = 0; k < 8; k++) acc[k] += __shfl_xor(acc[k], 16);
#pragma unroll
            for (int k = 0; k < 8; k++) acc[k] += __shfl_xor(acc[k], 32);
            if (g == 0) {
                float r = 1.0f / d;
                float o[8];
#pragma unroll
                for (int k = 0; k < 8; k++) o[k] = acc[k] * r;
                hs[(size_t)v * 16 + sub] = enc8(o);
            }
        }
    }
}

__device__ __forceinline__ void aggL_phase(const uint2* __restrict__ hs, const int* __restrict__ row_ptr,
        const int* __restrict__ ssrc, const float* __restrict__ deg, bf16* __restrict__ aggout, int n)
{
    const int wave = threadIdx.x >> 6, lane = threadIdx.x & 63;
    const int g = lane >> 4, sub = lane & 15;
    for (int b0 = blockIdx.x * 4; b0 < n; b0 += NBLK * 4) {
        int v = b0 + wave;
        if (v < n) {
            int e0 = row_ptr[v], e1 = row_ptr[v + 1];
            uint2 sv = hs[(size_t)v * 16 + sub];
            float d = deg[v];
            float acc[8];
#pragma unroll
            for (int k = 0; k < 8; k++) acc[k] = 0.f;
            for (int base = e0; base < e1; base += 16) {
                int mye = base + g * 4;
                int idx[4]; float w[4];
#pragma unroll
                for (int j = 0; j < 4; j++) {
                    int e = mye + j;
                    w[j] = (e < e1) ? 1.0f : 0.0f;
                    idx[j] = ssrc[e < e1 ? e : e1 - 1];
                }
                uint2 x0 = hs[(size_t)idx[0] * 16 + sub];
                uint2 x1 = hs[(size_t)idx[1] * 16 + sub];
                uint2 x2 = hs[(size_t)idx[2] * 16 + sub];
                uint2 x3 = hs[(size_t)idx[3] * 16 + sub];
                float f0[8], f1[8], f2[8], f3[8];
                dec8(x0, f0); dec8(x1, f1); dec8(x2, f2); dec8(x3, f3);
#pragma unroll
                for (int k = 0; k < 8; k++) acc[k] = fmaf(w[0], f0[k], acc[k]);
#pragma unroll
                for (int k = 0; k < 8; k++) acc[k] = fmaf(w[1], f1[k], acc[k]);
#pragma unroll
                for (int k = 0; k < 8; k++) acc[k] = fmaf(w[2], f2[k], acc[k]);
#pragma unroll
                for (int k = 0; k < 8; k++) acc[k] = fmaf(w[3], f3[k], acc[k]);
            }
#pragma unroll
            for (int k = 0; k < 8; k++) acc[k] += __shfl_xor(acc[k], 16);
#pragma unroll
            for (int k = 0; k < 8; k++) acc[k] += __shfl_xor(acc[k], 32);
            if (g == 0) {
                float fs[8];
                dec8(sv, fs);
                bf16x8 wv;
#pragma unroll
                for (int k = 0; k < 8; k++) wv[k] = (bf16)(acc[k] + fs[k] * d);
                *(bf16x8*)(aggout + (size_t)v * H + sub * 8) = wv;
            }
        }
    }
}

// ---- the mega kernel ----
__global__ __launch_bounds__(256, 2)
void k_mega(const float* __restrict__ node_feat, const float* __restrict__ degree,
            const float* __restrict__ Wn, const float* __restrict__ bn,
            const float* __restrict__ Wgcn, const float* __restrict__ bgcn,
            const float* __restrict__ Wpred, const float* __restrict__ bpred,
            const float* __restrict__ Wcls, const float* __restrict__ bcls,
            const int* __restrict__ src, const int* __restrict__ dst,
            uint2* __restrict__ h0g, uint2* __restrict__ hsb, bf16* __restrict__ aggb,
            int* __restrict__ cnt, int* __restrict__ row_ptr, int* __restrict__ nxt,
            int* __restrict__ ssrc, int* __restrict__ part,
            float* __restrict__ colsum, int* __restrict__ bar,
            float* __restrict__ out, int N, int E)
{
    __shared__ alignas(16) char shmem[52224];
    __shared__ float cs[128];
    __shared__ int shscan[256];
    bf16 (*As)[136] = (bf16(*)[136])shmem;
    bf16 (*Bs)[136] = (bf16(*)[136])(shmem + 17408);
    const int tid = threadIdx.x;
    const int bid = blockIdx.x;
    const int nT = (N + 255) >> 8;
    int ib = 0;

    // phase 1: gemm0 + hist
    gemm0_phase(node_feat, Wn, bn, h0g, colsum, N, As, Bs, cs);
    for (int i = bid * 256 + tid; i < E; i += NBLK * 256) atomicAdd(&cnt[dst[i]], 1);
    gbar(bar, ib++);

    // phase 2: scan1 (per-tile sums)
    if (bid < nT) {
        int i = bid * 256 + tid;
        shscan[tid] = (i < N) ? cnt[i] : 0;
        __syncthreads();
        for (int off = 128; off > 0; off >>= 1) {
            if (tid < off) shscan[tid] += shscan[tid + off];
            __syncthreads();
        }
        if (tid == 0) part[bid] = shscan[0];
    }
    gbar(bar, ib++);

    // phase 3: scan2 (exclusive scan of partials, block 0)
    if (bid == 0) {
        shscan[tid] = (tid < nT) ? part[tid] : 0;
        __syncthreads();
        for (int off = 1; off < 256; off <<= 1) {
            int v = (tid >= off) ? shscan[tid - off] : 0;
            __syncthreads();
            shscan[tid] += v;
            __syncthreads();
        }
        if (tid < nT) part[tid] = (tid == 0) ? 0 : shscan[tid - 1];
    }
    gbar(bar, ib++);

    // phase 4: scan3 (row_ptr, nxt)
    if (bid < nT) {
        int i = bid * 256 + tid;
        shscan[tid] = (i < N) ? cnt[i] : 0;
        __syncthreads();
        for (int off = 1; off < 256; off <<= 1) {
            int v = (tid >= off) ? shscan[tid - off] : 0;
            __syncthreads();
            shscan[tid] += v;
            __syncthreads();
        }
        int excl = part[bid] + ((tid == 0) ? 0 : shscan[tid - 1]);
        if (i < N) { row_ptr[i] = excl; nxt[i] = excl; }
        if (i == 0) row_ptr[N] = E;
    }
    gbar(bar, ib++);

    // phase 5: fill
    for (int i = bid * 256 + tid; i < E; i += NBLK * 256) {
        int p = atomicAdd(&nxt[dst[i]], 1);
        ssrc[p] = src[i];
    }
    gbar(bar, ib++);

    // phase 6: initial fusion
    agg0_phase(h0g, row_ptr, ssrc, degree, hsb, N);
    gbar(bar, ib++);

    // phases 7-12: 3 GCN layers
    aggL_phase(hsb, row_ptr, ssrc, degree, aggb, N);
    gbar(bar, ib++);
    gemmL_phase<true>(aggb, Wgcn, bgcn, degree, hsb, colsum + 1 * H, N, As, Bs, cs);
    gbar(bar, ib++);
    aggL_phase(hsb, row_ptr, ssrc, degree, aggb, N);
    gbar(bar, ib++);
    gemmL_phase<true>(aggb, Wgcn, bgcn, degree, hsb, colsum + 2 * H, N, As, Bs, cs);
    gbar(bar, ib++);
    aggL_phase(hsb, row_ptr, ssrc, degree, aggb, N);
    gbar(bar, ib++);
    gemmL_phase<false>(aggb, Wgcn, bgcn, degree, hsb, colsum + 3 * H, N, As, Bs, cs);
    gbar(bar, ib++);

    // phase 13: finisher (block 0)
    if (bid == 0) {
        float* g = (float*)shmem;       // 512
        float* g2 = g + 512;            // 128
        float* lg = g2 + 128;           // 2
        float invn = 1.0f / (float)N;
        for (int i = tid; i < 512; i += 256) g[i] = colsum[i] * invn;
        __syncthreads();
        if (tid < 128) {
            float acc = bpred[tid];
            for (int i = 0; i < 512; i++) acc += g[i] * Wpred[i * 128 + tid];
            g2[tid] = acc;
        }
        __syncthreads();
        if (tid < 2) {
            float l = bcls[tid];
            for (int j = 0; j < 128; j++) l += g2[j] * Wcls[j * 2 + tid];
            lg[tid] = l;
        }
        __syncthreads();
        if (tid == 0) {
            float m = fmaxf(lg[0], lg[1]);
            float e0 = expf(lg[0] - m), e1 = expf(lg[1] - m);
            float s = e0 + e1;
            out[0] = e0 / s;
            out[1] = e1 / s;
        }
    }
}

// ---------------- launch ----------------

extern "C" void kernel_launch(void* const* d_in, const int* in_sizes, int n_in,
                              void* d_out, int out_size, void* d_ws, size_t ws_size,
                              hipStream_t stream) {
    const float* node_feat = (const float*)d_in[0];
    const float* degree = (const float*)d_in[3];
    const float* Wn     = (const float*)d_in[4];
    const float* bn     = (const float*)d_in[5];
    const float* Wgcn   = (const float*)d_in[8];
    const float* bgcn   = (const float*)d_in[9];
    const float* Wpred  = (const float*)d_in[10];
    const float* bpred  = (const float*)d_in[11];
    const float* Wcls   = (const float*)d_in[12];
    const float* bcls   = (const float*)d_in[13];
    const int*   src    = (const int*)d_in[14];
    const int*   dst    = (const int*)d_in[15];
    float* out = (float*)d_out;

    const int N = in_sizes[3];
    const int E = in_sizes[14];
    (void)n_in; (void)out_size; (void)ws_size;

    char* p = (char*)d_ws;
    auto carve = [&](size_t bytes) { char* r = p; p += (bytes + 255) & ~(size_t)255; return r; };
    uint2* h0g    = (uint2*)carve((size_t)N * H);       // fp8 h0 gather table
    uint2* hsb    = (uint2*)carve((size_t)N * H);       // fp8 pre-scaled hidden table
    bf16*  aggb   = (bf16*)carve((size_t)N * H * 2);    // bf16 agg output -> GEMM A
    int*   row_ptr= (int*)carve((size_t)(N + 1) * 4);
    int*   nxt    = (int*)carve((size_t)N * 4);
    int*   ssrc   = (int*)carve((size_t)E * 4);
    // zeroed region: cnt + part + colsum + bar (single memset)
    int*   cnt    = (int*)carve((size_t)N * 4);
    int*   part   = (int*)carve(256 * 4);
    float* colsum = (float*)carve(512 * 4);
    int*   bar    = (int*)carve(64 * 4);
    size_t zlen = (size_t)((char*)(bar + 64) - (char*)cnt);
    hipMemsetAsync(cnt, 0, zlen, stream);

    hipLaunchKernelGGL(k_mega, dim3(NBLK), dim3(256), 0, stream,
                       node_feat, degree, Wn, bn, Wgcn, bgcn, Wpred, bpred, Wcls, bcls,
                       src, dst, h0g, hsb, aggb, cnt, row_ptr, nxt, ssrc, part,
                       colsum, bar, out, N, E);
}